// Round 2
// baseline (4317.330 us; speedup 1.0000x reference)
//
#include <hip/hip_runtime.h>
#include <hip/hip_bf16.h>

typedef __hip_bfloat16 bf16;

#define BB   256
#define NN   200
#define EE   1600
#define HH   256
#define TT   30
#define LL   30

__device__ inline float bf2f(bf16 v) { return __bfloat162float(v); }
__device__ inline float ldf(const float* p) { return *p; }
__device__ inline float ldf(const bf16* p) { return __bfloat162float(*p); }
__device__ inline void stf(float* p, float v) { *p = v; }
__device__ inline void stf(bf16* p, float v) { *p = __float2bfloat16(v); }

// ---------------- diagnostic (ws too small) ----------------
__global__ __launch_bounds__(256) void k_diag(float* out, int n, float v) {
    for (int i = blockIdx.x * 256 + threadIdx.x; i < n; i += gridDim.x * 256) out[i] = v;
}

// ---------------- degree / adjacency ----------------
__global__ __launch_bounds__(256) void k_deg(const int* __restrict__ ei, int* __restrict__ cnt) {
    int idx = blockIdx.x * 256 + threadIdx.x;           // B*E
    int b = idx / EE, e = idx % EE;
    int tg = ei[(long)b * 2 * EE + EE + e];
    atomicAdd(&cnt[b * NN + tg], 1);
}

__global__ __launch_bounds__(256) void k_dinv(const int* __restrict__ cnt, float* __restrict__ dinv) {
    int i = blockIdx.x * 256 + threadIdx.x;             // B*N
    dinv[i] = rsqrtf((float)cnt[i] + 1.0f);             // +1 self-loop
}

__global__ __launch_bounds__(256) void k_adj(const int* __restrict__ ei, const float* __restrict__ dinv,
                                             float* __restrict__ AdjF) {
    int idx = blockIdx.x * 256 + threadIdx.x;           // B*E
    int b = idx / EE, e = idx % EE;
    const int* eb = ei + (long)b * 2 * EE;
    int s = eb[e], tg = eb[EE + e];
    // duplicates of the same (s,tg) add IDENTICAL values -> order-independent -> deterministic
    atomicAdd(&AdjF[((long)b * NN + tg) * NN + s], dinv[b * NN + tg] * dinv[b * NN + s]);
}

__global__ __launch_bounds__(256) void k_adjself(const float* __restrict__ dinv, float* __restrict__ AdjF) {
    int idx = blockIdx.x * 256 + threadIdx.x;           // B*N
    int b = idx / NN, n = idx % NN;
    float d = dinv[idx];
    atomicAdd(&AdjF[((long)b * NN + n) * NN + n], d * d);
}

__global__ __launch_bounds__(256) void k_adjconv(const float* __restrict__ src, bf16* __restrict__ dst) {
    long i = (long)blockIdx.x * 256 + threadIdx.x;      // 10,240,000
    dst[i] = __float2bfloat16(src[i]);
}

// ---------------- m1 = node_features @ W1 (K=4) ----------------
__global__ __launch_bounds__(256) void k_m1(const float* __restrict__ nf, const float* __restrict__ W1,
                                            bf16* __restrict__ m1) {
    long idx = (long)blockIdx.x * 256 + threadIdx.x;    // B*N*H
    int h = idx & 255;
    long bn = idx >> 8;
    const float* x = nf + bn * 4;
    m1[idx] = __float2bfloat16(x[0] * W1[h] + x[1] * W1[256 + h] + x[2] * W1[512 + h] + x[3] * W1[768 + h]);
}

// ---------------- generic mixed GEMM: C = A @ (B or B^T) (+bias)(+relu) ----------------
// 64x64 tile, BK=16, 256 threads, 4x4 per thread; LDS/accumulate in f32.
template <bool BT, typename TA, typename TB, typename TC>
__global__ __launch_bounds__(256)
void gemm64(const TA* __restrict__ A, long aBatch, int lda,
            const TB* __restrict__ Bm, long bBatch, int ldb,
            TC* __restrict__ C, long cBatch, int ldc,
            const float* __restrict__ bias, long biasBatch,
            int M, int Nn, int K, int flags) {
    __shared__ float As[16][64];
    __shared__ float Bs[16][64];
    int bz = blockIdx.z;
    const TA* Ab = A + (long)bz * aBatch;
    const TB* Bb = Bm + (long)bz * bBatch;
    TC* Cb = C + (long)bz * cBatch;
    int m0 = blockIdx.y * 64, n0 = blockIdx.x * 64;
    int tid = threadIdx.x;
    int tr = tid >> 4, tc = tid & 15;
    float acc[4][4] = {};
    int la_m = tid >> 2;             // 0..63
    int la_k = (tid & 3) * 4;        // 0,4,8,12
    for (int k0 = 0; k0 < K; k0 += 16) {
#pragma unroll
        for (int j = 0; j < 4; ++j) {
            int kk = la_k + j;
            float v = 0.f;
            if (m0 + la_m < M && k0 + kk < K) v = ldf(&Ab[(long)(m0 + la_m) * lda + k0 + kk]);
            As[kk][la_m] = v;
        }
        if (!BT) {
            int n = tid & 63, kb = (tid >> 6) * 4;
#pragma unroll
            for (int j = 0; j < 4; ++j) {
                int kk = kb + j;
                float v = 0.f;
                if (k0 + kk < K && n0 + n < Nn) v = ldf(&Bb[(long)(k0 + kk) * ldb + n0 + n]);
                Bs[kk][n] = v;
            }
        } else {
            int n = tid >> 2, kb = (tid & 3) * 4;
#pragma unroll
            for (int j = 0; j < 4; ++j) {
                int kk = kb + j;
                float v = 0.f;
                if (k0 + kk < K && n0 + n < Nn) v = ldf(&Bb[(long)(n0 + n) * ldb + k0 + kk]);
                Bs[kk][n] = v;
            }
        }
        __syncthreads();
#pragma unroll
        for (int kk = 0; kk < 16; ++kk) {
            float4 a4 = *(const float4*)&As[kk][tr * 4];
            float4 b4 = *(const float4*)&Bs[kk][tc * 4];
            float a[4] = {a4.x, a4.y, a4.z, a4.w};
            float bb[4] = {b4.x, b4.y, b4.z, b4.w};
#pragma unroll
            for (int i = 0; i < 4; ++i)
#pragma unroll
                for (int j = 0; j < 4; ++j) acc[i][j] += a[i] * bb[j];
        }
        __syncthreads();
    }
#pragma unroll
    for (int i = 0; i < 4; ++i) {
        int m = m0 + tr * 4 + i;
        if (m >= M) continue;
#pragma unroll
        for (int j = 0; j < 4; ++j) {
            int n = n0 + tc * 4 + j;
            if (n >= Nn) continue;
            float v = acc[i][j];
            if (bias) v += bias[(long)bz * biasBatch + n];
            if (flags & 1) v = fmaxf(v, 0.f);
            stf(&Cb[(long)m * ldc + n], v);
        }
    }
}

// ---------------- attention + fused node-mean: per (b, head) block ----------------
__global__ __launch_bounds__(256) void k_attn(const bf16* __restrict__ qkv, float* __restrict__ gmean) {
    int b = blockIdx.x >> 2, hd = blockIdx.x & 3;
    __shared__ bf16 Ks[NN][66];
    __shared__ bf16 Vt[64][202];
    __shared__ float Qs[4][64];
    __shared__ float Ps[4][NN];
    __shared__ float Gp[4][64];
    for (int idx = threadIdx.x; idx < NN * 64; idx += 256) {
        int n = idx >> 6, d = idx & 63;
        long base = ((long)b * NN + n) * 768 + hd * 64 + d;
        Ks[n][d] = qkv[base + 256];
        Vt[d][n] = qkv[base + 512];
    }
    __syncthreads();
    int wv = threadIdx.x >> 6, lane = threadIdx.x & 63;
    float gacc = 0.f;
    for (int q = wv; q < NN; q += 4) {   // uniform trip count (50) for all 4 waves
        Qs[wv][lane] = bf2f(qkv[((long)b * NN + q) * 768 + hd * 64 + lane]);
        __syncthreads();
        float s0 = 0, s1 = 0, s2 = 0, s3 = 0;
        const bf16* r0 = Ks[lane];
        const bf16* r1 = Ks[lane + 64];
        const bf16* r2 = Ks[lane + 128];
        const bf16* r3 = Ks[(lane < 8) ? (lane + 192) : 0];
#pragma unroll 8
        for (int d2 = 0; d2 < 32; ++d2) {
            float2 qq = *(const float2*)&Qs[wv][2 * d2];
            __hip_bfloat162 k0 = *(const __hip_bfloat162*)(r0 + 2 * d2);
            __hip_bfloat162 k1 = *(const __hip_bfloat162*)(r1 + 2 * d2);
            __hip_bfloat162 k2 = *(const __hip_bfloat162*)(r2 + 2 * d2);
            __hip_bfloat162 k3 = *(const __hip_bfloat162*)(r3 + 2 * d2);
            s0 += qq.x * bf2f(k0.x) + qq.y * bf2f(k0.y);
            s1 += qq.x * bf2f(k1.x) + qq.y * bf2f(k1.y);
            s2 += qq.x * bf2f(k2.x) + qq.y * bf2f(k2.y);
            s3 += qq.x * bf2f(k3.x) + qq.y * bf2f(k3.y);
        }
        s0 *= 0.125f; s1 *= 0.125f; s2 *= 0.125f; s3 *= 0.125f;
        float mx = fmaxf(fmaxf(s0, s1), s2);
        if (lane < 8) mx = fmaxf(mx, s3);
#pragma unroll
        for (int off = 32; off; off >>= 1) mx = fmaxf(mx, __shfl_xor(mx, off));
        float e0 = expf(s0 - mx), e1 = expf(s1 - mx), e2 = expf(s2 - mx);
        float e3 = (lane < 8) ? expf(s3 - mx) : 0.f;
        float sum = e0 + e1 + e2 + e3;
#pragma unroll
        for (int off = 32; off; off >>= 1) sum += __shfl_xor(sum, off);
        float inv = 1.f / sum;
        Ps[wv][lane] = e0 * inv;
        Ps[wv][lane + 64] = e1 * inv;
        Ps[wv][lane + 128] = e2 * inv;
        if (lane < 8) Ps[wv][lane + 192] = e3 * inv;
        __syncthreads();
        float od = 0.f;
        const bf16* vr = Vt[lane];
#pragma unroll 4
        for (int j2 = 0; j2 < 100; ++j2) {
            float2 pp = *(const float2*)&Ps[wv][2 * j2];
            __hip_bfloat162 vv = *(const __hip_bfloat162*)(vr + 2 * j2);
            od += pp.x * bf2f(vv.x) + pp.y * bf2f(vv.y);
        }
        gacc += od;   // fused mean over nodes
    }
    Gp[wv][lane] = gacc;
    __syncthreads();
    if (wv == 0) {
        float s = Gp[0][lane] + Gp[1][lane] + Gp[2][lane] + Gp[3][lane];
        gmean[b * 256 + hd * 64 + lane] = s * (1.0f / 200.0f);
    }
}

__global__ __launch_bounds__(256) void k_bsum(const float* __restrict__ bih, const float* __restrict__ bhh,
                                              float* __restrict__ bsum) {
    int i = blockIdx.x * 256 + threadIdx.x;             // 5*2*1024
    bsum[i] = bih[i] + bhh[i];
}

// ---------------- fused LSTM step ----------------
template <int LAYER>
__global__ __launch_bounds__(256)
void lstm_step(const bf16* __restrict__ zx, const float* __restrict__ xf,
               const float* __restrict__ Wih0_, const float* __restrict__ Whh_,
               const bf16* __restrict__ hprev, long hprevBranch,
               bf16* __restrict__ hnext, long hnextBranch,
               float* __restrict__ cst, int t) {
    __shared__ float hs[32][32];     // hs[kk][b]
    __shared__ float ws[4][32][32];  // ws[g][kk][j]
    int k5 = blockIdx.z;
    int b0 = blockIdx.y * 32;
    int j0 = blockIdx.x * 32;
    int tid = threadIdx.x;
    int tr = tid >> 4, tc = tid & 15;
    float acc[4][2][2] = {};
    const bf16* hp = hprev + (long)k5 * hprevBranch + (long)b0 * 256;
    const float* wp = Whh_ + ((long)(k5 * 2 + LAYER) * 1024 + j0) * 256;
    int lb = tid >> 3;            // 0..31
    int lk = (tid & 7) * 4;       // 0..28
    for (int kk0 = 0; kk0 < 256; kk0 += 32) {
#pragma unroll
        for (int j = 0; j < 4; ++j) hs[lk + j][lb] = bf2f(hp[(long)lb * 256 + kk0 + lk + j]);
#pragma unroll
        for (int g = 0; g < 4; ++g)
#pragma unroll
            for (int j = 0; j < 4; ++j)
                ws[g][lk + j][lb] = wp[(long)(g * 256 + lb) * 256 + kk0 + lk + j];
        __syncthreads();
#pragma unroll
        for (int kk = 0; kk < 32; ++kk) {
            float2 a = *(const float2*)&hs[kk][tr * 2];
#pragma unroll
            for (int g = 0; g < 4; ++g) {
                float2 w = *(const float2*)&ws[g][kk][tc * 2];
                acc[g][0][0] += a.x * w.x; acc[g][0][1] += a.x * w.y;
                acc[g][1][0] += a.y * w.x; acc[g][1][1] += a.y * w.y;
            }
        }
        __syncthreads();
    }
#pragma unroll
    for (int i = 0; i < 2; ++i) {
        int b = b0 + tr * 2 + i;
        float x0 = 0.f, x1 = 0.f;
        if (LAYER == 0) {
            const float* xr = xf + ((long)(k5 * 256 + b) * TT + t) * 2;
            x0 = xr[0]; x1 = xr[1];
        }
#pragma unroll
        for (int j = 0; j < 2; ++j) {
            int jj = j0 + tc * 2 + j;
            float z[4];
#pragma unroll
            for (int g = 0; g < 4; ++g) {
                float zz = acc[g][i][j];
                if (LAYER == 0) {
                    const float* wr = Wih0_ + ((long)(k5 * 1024) + g * 256 + jj) * 258;
                    zz += bf2f(zx[((long)(k5 * 256) + b) * 1024 + g * 256 + jj]) + x0 * wr[0] + x1 * wr[1];
                } else {
                    zz += bf2f(zx[((long)k5 * (TT * 256) + t * 256 + b) * 1024 + g * 256 + jj]);
                }
                z[g] = zz;
            }
            long ci = ((long)(k5 * 256) + b) * 256 + jj;
            float cprev = cst[ci];
            float ig = 1.f / (1.f + expf(-z[0]));
            float fg = 1.f / (1.f + expf(-z[1]));
            float gg = tanhf(z[2]);
            float og = 1.f / (1.f + expf(-z[3]));
            float c = fg * cprev + ig * gg;
            float h = og * tanhf(c);
            cst[ci] = c;
            hnext[(long)k5 * hnextBranch + (long)b * 256 + jj] = __float2bfloat16(h);
        }
    }
}

// ---------------- heads ----------------
__global__ __launch_bounds__(256) void k_heads(const bf16* __restrict__ lasth,
                                               const float* __restrict__ fcW_pv, const float* __restrict__ fcb_pv,
                                               const float* __restrict__ fcW_s, const float* __restrict__ fcb_s,
                                               float* __restrict__ out) {
    int b = blockIdx.x;
    __shared__ float hl[5][257];
    for (int idx = threadIdx.x; idx < 5 * 256; idx += 256) {
        int k = idx >> 8, h = idx & 255;
        hl[k][h] = bf2f(lasth[((long)k * 256 + b) * 256 + h]);
    }
    __syncthreads();
    int i = threadIdx.x;
    if (i < 210) {
        int k, o, l, c;
        const float* w;
        float bias;
        bool sig = false;
        if (i < 60)       { k = 0; o = i;       w = fcW_pv + o * 256;        bias = fcb_pv[o];       l = o >> 1; c = o & 1; }
        else if (i < 120) { k = 1; o = i - 60;  w = fcW_pv + (60 + o) * 256; bias = fcb_pv[60 + o];  l = o >> 1; c = 2 + (o & 1); }
        else if (i < 150) { k = 2; o = i - 120; w = fcW_s + o * 256;         bias = fcb_s[o];        l = o; c = 4; }
        else if (i < 180) { k = 3; o = i - 150; w = fcW_s + (30 + o) * 256;  bias = fcb_s[30 + o];   l = o; c = 5; sig = true; }
        else              { k = 4; o = i - 180; w = fcW_s + (60 + o) * 256;  bias = fcb_s[60 + o];   l = o; c = 6; sig = true; }
        float acc = bias;
        for (int h = 0; h < 256; ++h) acc += hl[k][h] * w[h];
        if (sig) acc = 1.f / (1.f + expf(-acc));
        out[(long)b * 210 + l * 7 + c] = acc;
    }
}

// ---------------- launch ----------------
extern "C" void kernel_launch(void* const* d_in, const int* in_sizes, int n_in,
                              void* d_out, int out_size, void* d_ws, size_t ws_size,
                              hipStream_t stream) {
    (void)in_sizes; (void)n_in;
    const float* x_feats   = (const float*)d_in[0];
    const float* node_feat = (const float*)d_in[1];
    const int*   edge_idx  = (const int*)d_in[2];
    const float* gcn_W1    = (const float*)d_in[3];
    const float* gcn_b1    = (const float*)d_in[4];
    const float* gcn_W2    = (const float*)d_in[5];
    const float* gcn_b2    = (const float*)d_in[6];
    const float* attn_in_w = (const float*)d_in[7];
    const float* attn_in_b = (const float*)d_in[8];
    const float* attn_out_w= (const float*)d_in[9];
    const float* attn_out_b= (const float*)d_in[10];
    const float* Wih0      = (const float*)d_in[11];
    const float* Wih1      = (const float*)d_in[12];
    const float* Whh       = (const float*)d_in[13];
    const float* bih       = (const float*)d_in[14];
    const float* bhh       = (const float*)d_in[15];
    const float* fcW_pv    = (const float*)d_in[16];
    const float* fcb_pv    = (const float*)d_in[17];
    const float* fcW_s     = (const float*)d_in[18];
    const float* fcb_s     = (const float*)d_in[19];
    float* out = (float*)d_out;

    // Workspace layout (f32-slot offsets). Total = 33,249,280 f32 = 133.0 MB.
    const size_t NEEDED = 33249280ULL * 4ULL;
    if (ws_size < NEEDED) {   // diagnostic: report ws_size (in MiB) through the output
        k_diag<<<210, 256, 0, stream>>>(out, out_size, (float)(ws_size >> 20));
        return;
    }
    float* W = (float*)d_ws;
    float* AdjF  = W;                                   // 10,240,000 f32 (in R1)
    bf16*  R1    = (bf16*)W;                            // 39,321,600 bf16: m1/m2 -> qkv -> zin1
    bf16*  m1    = R1;                                  // 13,107,200 bf16
    bf16*  m2    = R1;                                  // (m1 dead by then)
    bf16*  qkv   = R1;                                  // 39,321,600 bf16
    bf16*  zin1  = R1;                                  // 39,321,600 bf16
    bf16*  Adjb  = (bf16*)(W + 19660800);               // 10,240,000 bf16; reused as y0
    bf16*  y0    = Adjb;                                // 9,830,400 bf16
    bf16*  R2    = (bf16*)(W + 24780800);               // 13,107,200 bf16: h1 -> g
    float* dinv  = W + 31334400;                        // 51,200
    int*   degc  = (int*)(W + 31385600);                // 51,200
    float* gmean = W + 31436800;                        // 65,536
    float* gfeat = W + 31502336;                        // 65,536
    float* bsum  = W + 31567872;                        // 10,240
    bf16*  gpart = (bf16*)(W + 31578112);               // 1,310,720 bf16
    bf16*  hz    = (bf16*)(W + 32233472);               // 65,536 bf16 (zero h)
    float* c0    = W + 32266240;                        // 327,680
    float* c1    = W + 32593920;                        // 327,680
    bf16*  h1a   = (bf16*)(W + 32921600);               // 327,680 bf16
    bf16*  h1b   = (bf16*)(W + 33085440);               // 327,680 bf16

    hipMemsetAsync(AdjF, 0, (size_t)10240000 * 4, stream);
    hipMemsetAsync(degc, 0, (size_t)51200 * 4, stream);
    hipMemsetAsync(hz,   0, (size_t)65536 * 2, stream);
    hipMemsetAsync(c0,   0, (size_t)327680 * 4, stream);
    hipMemsetAsync(c1,   0, (size_t)327680 * 4, stream);

    k_deg<<<1600, 256, 0, stream>>>(edge_idx, degc);
    k_dinv<<<200, 256, 0, stream>>>(degc, dinv);
    k_adj<<<1600, 256, 0, stream>>>(edge_idx, dinv, AdjF);
    k_adjself<<<200, 256, 0, stream>>>(dinv, AdjF);
    k_adjconv<<<40000, 256, 0, stream>>>(AdjF, Adjb);
    k_m1<<<51200, 256, 0, stream>>>(node_feat, gcn_W1, m1);

    // h1 = relu(Adj @ m1 + b1)   [batched 256: M=200,N=256,K=200]
    gemm64<false, bf16, bf16, bf16><<<dim3(4, 4, 256), 256, 0, stream>>>(
        Adjb, 40000, 200, m1, 51200, 256, R2, 51200, 256, gcn_b1, 0, 200, 256, 200, 1);
    // m2 = h1 @ W2               [M=51200,N=256,K=256]
    gemm64<false, bf16, float, bf16><<<dim3(4, 800, 1), 256, 0, stream>>>(
        R2, 0, 256, gcn_W2, 0, 256, m2, 0, 256, nullptr, 0, 51200, 256, 256, 0);
    // g = relu(Adj @ m2 + b2)    -> R2 (h1 dead)
    gemm64<false, bf16, bf16, bf16><<<dim3(4, 4, 256), 256, 0, stream>>>(
        Adjb, 40000, 200, m2, 51200, 256, R2, 51200, 256, gcn_b2, 0, 200, 256, 200, 1);
    // qkv = g @ attn_in_w^T + b  [M=51200,N=768,K=256]
    gemm64<true, bf16, float, bf16><<<dim3(12, 800, 1), 256, 0, stream>>>(
        R2, 0, 256, attn_in_w, 0, 256, qkv, 0, 768, attn_in_b, 0, 51200, 768, 256, 0);
    k_attn<<<1024, 256, 0, stream>>>(qkv, gmean);
    // gfeat = gmean @ attn_out_w^T + attn_out_b   (mean commutes with the linear proj)
    gemm64<true, float, float, float><<<dim3(4, 4, 1), 256, 0, stream>>>(
        gmean, 0, 256, attn_out_w, 0, 256, gfeat, 0, 256, attn_out_b, 0, 256, 256, 256, 0);
    k_bsum<<<40, 256, 0, stream>>>(bih, bhh, bsum);
    // gpart[k] = gfeat @ Wih0[k][:,2:]^T + (bih0+bhh0)   [batch 5: M=256,N=1024,K=256]
    gemm64<true, float, float, bf16><<<dim3(16, 4, 5), 256, 0, stream>>>(
        gfeat, 0, 256, Wih0 + 2, 264192, 258, gpart, 262144, 1024, bsum, 2048, 256, 1024, 256, 0);
    // layer-0 recurrence (h per step -> y0, overwrites dead Adjb)
    for (int t = 0; t < TT; ++t) {
        const bf16* hp = t ? (y0 + (size_t)(t - 1) * 65536) : hz;
        long hpb = t ? 1966080L : 0L;
        lstm_step<0><<<dim3(8, 8, 5), 256, 0, stream>>>(gpart, x_feats, Wih0, Whh,
                                                        hp, hpb, y0 + (size_t)t * 65536, 1966080L, c0, t);
    }
    // zin1 = y0 @ Wih1^T + (bih1+bhh1)   [batch 5: M=7680,N=1024,K=256] (overwrites dead qkv)
    gemm64<true, bf16, float, bf16><<<dim3(16, 120, 5), 256, 0, stream>>>(
        y0, 1966080, 256, Wih1, 262144, 256, zin1, 7864320, 1024, bsum + 1024, 2048, 7680, 1024, 256, 0);
    // layer-1 recurrence; ping-pong; last hidden in h1b (t=29 odd)
    for (int t = 0; t < TT; ++t) {
        const bf16* hp = (t == 0) ? hz : ((t & 1) ? h1a : h1b);
        long hpb = (t == 0) ? 0L : 65536L;
        bf16* hn = (t & 1) ? h1b : h1a;
        lstm_step<1><<<dim3(8, 8, 5), 256, 0, stream>>>(zin1, nullptr, nullptr, Whh,
                                                        hp, hpb, hn, 65536L, c1, t);
    }
    k_heads<<<256, 256, 0, stream>>>(h1b, fcW_pv, fcb_pv, fcW_s, fcb_s, out);
}

// Round 3
// 1682.893 us; speedup vs baseline: 2.5654x; 2.5654x over previous
//
#include <hip/hip_runtime.h>
#include <hip/hip_bf16.h>

typedef __hip_bfloat16 bf16;
typedef __bf16 bh8 __attribute__((ext_vector_type(8)));
typedef float f32x4 __attribute__((ext_vector_type(4)));

#define BBATCH 256
#define NN   200
#define EE   1600

#define GLOAD16(gp, lp) __builtin_amdgcn_global_load_lds( \
    (const __attribute__((address_space(1))) void*)(gp),  \
    (__attribute__((address_space(3))) void*)(lp), 16, 0, 0)

__device__ inline float bf2f(bf16 v) { return __bfloat162float(v); }
__device__ inline float ldf(const float* p) { return *p; }
__device__ inline float ldf(const bf16* p) { return __bfloat162float(*p); }
__device__ inline void stf(float* p, float v) { *p = v; }
__device__ inline void stf(bf16* p, float v) { *p = __float2bfloat16(v); }

// ---------------- diagnostic (ws too small) ----------------
__global__ __launch_bounds__(256) void k_diag(float* out, int n, float v) {
    for (int i = blockIdx.x * 256 + threadIdx.x; i < n; i += gridDim.x * 256) out[i] = v;
}

// ---------------- degree / adjacency ----------------
__global__ __launch_bounds__(256) void k_deg(const int* __restrict__ ei, int* __restrict__ cnt) {
    int idx = blockIdx.x * 256 + threadIdx.x;           // B*E
    int b = idx / EE, e = idx % EE;
    int tg = ei[(long)b * 2 * EE + EE + e];
    atomicAdd(&cnt[b * NN + tg], 1);
}

__global__ __launch_bounds__(256) void k_dinv(const int* __restrict__ cnt, float* __restrict__ dinv) {
    int i = blockIdx.x * 256 + threadIdx.x;             // B*N
    dinv[i] = rsqrtf((float)cnt[i] + 1.0f);
}

__global__ __launch_bounds__(256) void k_adj(const int* __restrict__ ei, const float* __restrict__ dinv,
                                             float* __restrict__ AdjF) {
    int idx = blockIdx.x * 256 + threadIdx.x;           // B*E
    int b = idx / EE, e = idx % EE;
    const int* eb = ei + (long)b * 2 * EE;
    int s = eb[e], tg = eb[EE + e];
    // duplicate (s,tg) edges add IDENTICAL values -> order-independent -> deterministic
    atomicAdd(&AdjF[((long)b * NN + tg) * NN + s], dinv[b * NN + tg] * dinv[b * NN + s]);
}

__global__ __launch_bounds__(256) void k_adjself(const float* __restrict__ dinv, float* __restrict__ AdjF) {
    int idx = blockIdx.x * 256 + threadIdx.x;           // B*N
    int b = idx / NN, n = idx % NN;
    float d = dinv[idx];
    atomicAdd(&AdjF[((long)b * NN + n) * NN + n], d * d);
}

// AdjF [b][200][200] f32 -> Adjb [b][256][224] bf16 zero-padded
__global__ __launch_bounds__(256) void k_adjconv(const float* __restrict__ AdjF, bf16* __restrict__ Adjb) {
    long idx = (long)blockIdx.x * 256 + threadIdx.x;    // 256*256*224
    int col = idx % 224;
    int row = (idx / 224) & 255;
    int b = idx / (224 * 256);
    float v = (row < NN && col < NN) ? AdjF[((long)b * NN + row) * NN + col] : 0.f;
    Adjb[idx] = __float2bfloat16(v);
}

// m1t[b][h=256][node k=224] = (node_features @ W1)^T, zero-padded
__global__ __launch_bounds__(256) void k_m1t(const float* __restrict__ nf, const float* __restrict__ W1,
                                             bf16* __restrict__ m1t) {
    long idx = (long)blockIdx.x * 256 + threadIdx.x;    // 256*256*224
    int node = idx % 224;
    int h = (idx / 224) & 255;
    int b = idx / (224 * 256);
    float v = 0.f;
    if (node < NN) {
        const float* x = nf + ((long)b * NN + node) * 4;
        v = x[0] * W1[h] + x[1] * W1[256 + h] + x[2] * W1[512 + h] + x[3] * W1[768 + h];
    }
    m1t[idx] = __float2bfloat16(v);
}

// ---------------- weight conversions ----------------
__global__ __launch_bounds__(256) void k_conv(const float* __restrict__ s, bf16* __restrict__ d, int n) {
    int i = blockIdx.x * 256 + threadIdx.x;
    if (i < n) d[i] = __float2bfloat16(s[i]);
}

__global__ __launch_bounds__(256) void k_convT(const float* __restrict__ W2, bf16* __restrict__ w2t) {
    int i = blockIdx.x * 256 + threadIdx.x;             // 65536: i = n*256+k
    w2t[i] = __float2bfloat16(W2[((i & 255) << 8) + (i >> 8)]);
}

__global__ __launch_bounds__(256) void k_bsum(const float* __restrict__ bih, const float* __restrict__ bhh,
                                              float* __restrict__ bsum) {
    int i = blockIdx.x * 256 + threadIdx.x;             // 10240
    bsum[i] = bih[i] + bhh[i];
}

// ---------------- MFMA GEMM: C = A @ Bt^T (+bias)(+relu), bf16 in/out, f32 accum ----------
// A [.][lda] k-contig; Bt [n][ldb] k-contig; 128x128 tile, BK=32, 4 waves (2x2).
template<int BM, int BN, bool RELU, bool CT>
__global__ __launch_bounds__(256)
void mgemm(const bf16* __restrict__ A, long aBatch, int lda,
           const bf16* __restrict__ Bt, long bBatch, int ldb,
           bf16* __restrict__ C, long cBatch, int ldc,
           const float* __restrict__ bias, long biasBatch,
           int K, int Mvalid)
{
    constexpr int ACH = BM / 16, TCH = BM / 16 + BN / 16, PW = TCH / 4;
    constexpr int FM = BM / 32, FN = BN / 32;
    __shared__ bf16 Al[BM][32];
    __shared__ bf16 Bl[BN][32];
    int bz = blockIdx.z;
    const bf16* Ab = A + (long)bz * aBatch + (long)blockIdx.y * BM * lda;
    const bf16* Bb = Bt + (long)bz * bBatch + (long)blockIdx.x * BN * ldb;
    int tid = threadIdx.x, w = tid >> 6, l = tid & 63;
    int wm = w >> 1, wn = w & 1;
    int lrow = l >> 2, lk8 = (l & 3) * 8;
    f32x4 acc[FM][FN] = {};
    for (int k0 = 0; k0 < K; k0 += 32) {
#pragma unroll
        for (int cc = 0; cc < PW; ++cc) {
            int c = w * PW + cc;
            if (c < ACH) GLOAD16(Ab + (long)(c * 16 + lrow) * lda + k0 + lk8, ((char*)&Al[0][0]) + c * 1024);
            else { int bc = c - ACH; GLOAD16(Bb + (long)(bc * 16 + lrow) * ldb + k0 + lk8, ((char*)&Bl[0][0]) + bc * 1024); }
        }
        __syncthreads();
        bh8 af[FM], bfv[FN];
#pragma unroll
        for (int i = 0; i < FM; ++i) af[i] = *(const bh8*)&Al[wm * (BM / 2) + i * 16 + (l & 15)][(l >> 4) * 8];
#pragma unroll
        for (int j = 0; j < FN; ++j) bfv[j] = *(const bh8*)&Bl[wn * (BN / 2) + j * 16 + (l & 15)][(l >> 4) * 8];
#pragma unroll
        for (int i = 0; i < FM; ++i)
#pragma unroll
            for (int j = 0; j < FN; ++j)
                acc[i][j] = __builtin_amdgcn_mfma_f32_16x16x32_bf16(af[i], bfv[j], acc[i][j], 0, 0, 0);
        __syncthreads();
    }
    bf16* Cb = C + (long)bz * cBatch;
    int mq = blockIdx.y * BM + wm * (BM / 2);
    int nq = blockIdx.x * BN + wn * (BN / 2);
#pragma unroll
    for (int i = 0; i < FM; ++i) {
#pragma unroll
        for (int j = 0; j < FN; ++j) {
            int n = nq + j * 16 + (l & 15);
            float bv = bias ? bias[(long)bz * biasBatch + n] : 0.f;
            int m0 = mq + i * 16 + (l >> 4) * 4;
#pragma unroll
            for (int r = 0; r < 4; ++r) {
                int m = m0 + r;
                if (m < Mvalid) {
                    float v = acc[i][j][r] + bv;
                    if (RELU) v = fmaxf(v, 0.f);
                    if (CT) Cb[(long)n * ldc + m] = __float2bfloat16(v);
                    else    Cb[(long)m * ldc + n] = __float2bfloat16(v);
                }
            }
        }
    }
}

// ---------------- MFMA LSTM step: z = h@Whh^T (+zx)(+x·Wx), gates, cell update ----------
// grid (8 j-tiles, 4 b-tiles, 5 branches); tile: 64 batch x (32 j x 4 gates)
template<int LAYER>
__global__ __launch_bounds__(256)
void k_lstm(const bf16* __restrict__ hprev, long hprevS,
            const bf16* __restrict__ whhb,        // [5][2][1024][256] bf16
            const bf16* __restrict__ zx, long zxS, // [k5][...][b][1024]
            const float* __restrict__ xf,         // [5][256][30][2]
            const float* __restrict__ Wih0_,      // [5][1024][258]
            float* __restrict__ cst,              // [5][256][256]
            bf16* __restrict__ hnext, long hnextS,
            int t)
{
    __shared__ bf16 Al[64][32];
    __shared__ bf16 Bl[128][32];
    __shared__ float Zl[64][132];
    int k5 = blockIdx.z, b0 = blockIdx.y * 64, j0 = blockIdx.x * 32;
    int tid = threadIdx.x, w = tid >> 6, l = tid & 63;
    int wm = w >> 1, wn = w & 1;
    int lrow = l >> 2, lk8 = (l & 3) * 8;
    const bf16* Ab = hprev + (long)k5 * hprevS + (long)b0 * 256;
    const bf16* Bb = whhb + (long)(k5 * 2 + LAYER) * 262144;
    f32x4 acc[2][4] = {};
    for (int k0 = 0; k0 < 256; k0 += 32) {
#pragma unroll
        for (int cc = 0; cc < 3; ++cc) {
            int c = w * 3 + cc;
            if (c < 4) GLOAD16(Ab + (long)(c * 16 + lrow) * 256 + k0 + lk8, ((char*)&Al[0][0]) + c * 1024);
            else {
                int bc = c - 4;                      // 0..7; B-tile row nn = bc*16+lrow
                int gate = bc >> 1;
                int row = gate * 256 + j0 + (bc & 1) * 16 + lrow;   // Whh row
                GLOAD16(Bb + (long)row * 256 + k0 + lk8, ((char*)&Bl[0][0]) + bc * 1024);
            }
        }
        __syncthreads();
        bh8 af[2], bfv[4];
#pragma unroll
        for (int i = 0; i < 2; ++i) af[i] = *(const bh8*)&Al[wm * 32 + i * 16 + (l & 15)][(l >> 4) * 8];
#pragma unroll
        for (int j = 0; j < 4; ++j) bfv[j] = *(const bh8*)&Bl[wn * 64 + j * 16 + (l & 15)][(l >> 4) * 8];
#pragma unroll
        for (int i = 0; i < 2; ++i)
#pragma unroll
            for (int j = 0; j < 4; ++j)
                acc[i][j] = __builtin_amdgcn_mfma_f32_16x16x32_bf16(af[i], bfv[j], acc[i][j], 0, 0, 0);
        __syncthreads();
    }
#pragma unroll
    for (int i = 0; i < 2; ++i)
#pragma unroll
        for (int j = 0; j < 4; ++j)
#pragma unroll
            for (int r = 0; r < 4; ++r)
                Zl[wm * 32 + i * 16 + (l >> 4) * 4 + r][wn * 64 + j * 16 + (l & 15)] = acc[i][j][r];
    __syncthreads();
    int jj = tid & 31, bq = tid >> 5;
    int jg = j0 + jj;
#pragma unroll
    for (int i = 0; i < 8; ++i) {
        int bl = bq + i * 8;
        int bg = b0 + bl;
        const bf16* zp = zx + (long)k5 * zxS + (long)bg * 1024;
        float z[4];
#pragma unroll
        for (int g = 0; g < 4; ++g) z[g] = Zl[bl][g * 32 + jj] + bf2f(zp[g * 256 + jg]);
        if (LAYER == 0) {
            const float* xr = xf + ((long)(k5 * 256 + bg) * 30 + t) * 2;
            float x0 = xr[0], x1 = xr[1];
#pragma unroll
            for (int g = 0; g < 4; ++g) {
                const float* wr = Wih0_ + ((long)k5 * 1024 + g * 256 + jg) * 258;
                z[g] += x0 * wr[0] + x1 * wr[1];
            }
        }
        long ci = ((long)(k5 * 256 + bg)) * 256 + jg;
        float cprev = cst[ci];
        float ig = 1.f / (1.f + expf(-z[0]));
        float fg = 1.f / (1.f + expf(-z[1]));
        float gg = tanhf(z[2]);
        float og = 1.f / (1.f + expf(-z[3]));
        float c = fg * cprev + ig * gg;
        float h = og * tanhf(c);
        cst[ci] = c;
        hnext[(long)k5 * hnextS + (long)bg * 256 + jg] = __float2bfloat16(h);
    }
}

// ---------------- small f32 GEMM (kept for tiny gfeat/gpart) ----------------
template <bool BT, typename TA, typename TB, typename TC>
__global__ __launch_bounds__(256)
void gemm64(const TA* __restrict__ A, long aBatch, int lda,
            const TB* __restrict__ Bm, long bBatch, int ldb,
            TC* __restrict__ C, long cBatch, int ldc,
            const float* __restrict__ bias, long biasBatch,
            int M, int Nn, int K, int flags) {
    __shared__ float As[16][64];
    __shared__ float Bs[16][64];
    int bz = blockIdx.z;
    const TA* Ab = A + (long)bz * aBatch;
    const TB* Bb = Bm + (long)bz * bBatch;
    TC* Cb = C + (long)bz * cBatch;
    int m0 = blockIdx.y * 64, n0 = blockIdx.x * 64;
    int tid = threadIdx.x;
    int tr = tid >> 4, tc = tid & 15;
    float acc[4][4] = {};
    int la_m = tid >> 2;
    int la_k = (tid & 3) * 4;
    for (int k0 = 0; k0 < K; k0 += 16) {
#pragma unroll
        for (int j = 0; j < 4; ++j) {
            int kk = la_k + j;
            float v = 0.f;
            if (m0 + la_m < M && k0 + kk < K) v = ldf(&Ab[(long)(m0 + la_m) * lda + k0 + kk]);
            As[kk][la_m] = v;
        }
        if (!BT) {
            int n = tid & 63, kb = (tid >> 6) * 4;
#pragma unroll
            for (int j = 0; j < 4; ++j) {
                int kk = kb + j;
                float v = 0.f;
                if (k0 + kk < K && n0 + n < Nn) v = ldf(&Bb[(long)(k0 + kk) * ldb + n0 + n]);
                Bs[kk][n] = v;
            }
        } else {
            int n = tid >> 2, kb = (tid & 3) * 4;
#pragma unroll
            for (int j = 0; j < 4; ++j) {
                int kk = kb + j;
                float v = 0.f;
                if (k0 + kk < K && n0 + n < Nn) v = ldf(&Bb[(long)(n0 + n) * ldb + k0 + kk]);
                Bs[kk][n] = v;
            }
        }
        __syncthreads();
#pragma unroll
        for (int kk = 0; kk < 16; ++kk) {
            float4 a4 = *(const float4*)&As[kk][tr * 4];
            float4 b4 = *(const float4*)&Bs[kk][tc * 4];
            float a[4] = {a4.x, a4.y, a4.z, a4.w};
            float bb[4] = {b4.x, b4.y, b4.z, b4.w};
#pragma unroll
            for (int i = 0; i < 4; ++i)
#pragma unroll
                for (int j = 0; j < 4; ++j) acc[i][j] += a[i] * bb[j];
        }
        __syncthreads();
    }
#pragma unroll
    for (int i = 0; i < 4; ++i) {
        int m = m0 + tr * 4 + i;
        if (m >= M) continue;
#pragma unroll
        for (int j = 0; j < 4; ++j) {
            int n = n0 + tc * 4 + j;
            if (n >= Nn) continue;
            float v = acc[i][j];
            if (bias) v += bias[(long)bz * biasBatch + n];
            if (flags & 1) v = fmaxf(v, 0.f);
            stf(&Cb[(long)m * ldc + n], v);
        }
    }
}

// ---------------- attention + fused node-mean: per (b, head) block ----------------
__global__ __launch_bounds__(256) void k_attn(const bf16* __restrict__ qkv, float* __restrict__ gmean) {
    int b = blockIdx.x >> 2, hd = blockIdx.x & 3;
    __shared__ bf16 Ks[NN][66];
    __shared__ bf16 Vt[64][202];
    __shared__ float Qs[4][64];
    __shared__ float Ps[4][NN];
    __shared__ float Gp[4][64];
    for (int idx = threadIdx.x; idx < NN * 64; idx += 256) {
        int n = idx >> 6, d = idx & 63;
        long base = ((long)b * NN + n) * 768 + hd * 64 + d;
        Ks[n][d] = qkv[base + 256];
        Vt[d][n] = qkv[base + 512];
    }
    __syncthreads();
    int wv = threadIdx.x >> 6, lane = threadIdx.x & 63;
    float gacc = 0.f;
    for (int q = wv; q < NN; q += 4) {
        Qs[wv][lane] = bf2f(qkv[((long)b * NN + q) * 768 + hd * 64 + lane]);
        __syncthreads();
        float s0 = 0, s1 = 0, s2 = 0, s3 = 0;
        const bf16* r0 = Ks[lane];
        const bf16* r1 = Ks[lane + 64];
        const bf16* r2 = Ks[lane + 128];
        const bf16* r3 = Ks[(lane < 8) ? (lane + 192) : 0];
#pragma unroll 8
        for (int d2 = 0; d2 < 32; ++d2) {
            float2 qq = *(const float2*)&Qs[wv][2 * d2];
            __hip_bfloat162 k0 = *(const __hip_bfloat162*)(r0 + 2 * d2);
            __hip_bfloat162 k1 = *(const __hip_bfloat162*)(r1 + 2 * d2);
            __hip_bfloat162 k2 = *(const __hip_bfloat162*)(r2 + 2 * d2);
            __hip_bfloat162 k3 = *(const __hip_bfloat162*)(r3 + 2 * d2);
            s0 += qq.x * bf2f(k0.x) + qq.y * bf2f(k0.y);
            s1 += qq.x * bf2f(k1.x) + qq.y * bf2f(k1.y);
            s2 += qq.x * bf2f(k2.x) + qq.y * bf2f(k2.y);
            s3 += qq.x * bf2f(k3.x) + qq.y * bf2f(k3.y);
        }
        s0 *= 0.125f; s1 *= 0.125f; s2 *= 0.125f; s3 *= 0.125f;
        float mx = fmaxf(fmaxf(s0, s1), s2);
        if (lane < 8) mx = fmaxf(mx, s3);
#pragma unroll
        for (int off = 32; off; off >>= 1) mx = fmaxf(mx, __shfl_xor(mx, off));
        float e0 = expf(s0 - mx), e1 = expf(s1 - mx), e2 = expf(s2 - mx);
        float e3 = (lane < 8) ? expf(s3 - mx) : 0.f;
        float sum = e0 + e1 + e2 + e3;
#pragma unroll
        for (int off = 32; off; off >>= 1) sum += __shfl_xor(sum, off);
        float inv = 1.f / sum;
        Ps[wv][lane] = e0 * inv;
        Ps[wv][lane + 64] = e1 * inv;
        Ps[wv][lane + 128] = e2 * inv;
        if (lane < 8) Ps[wv][lane + 192] = e3 * inv;
        __syncthreads();
        float od = 0.f;
        const bf16* vr = Vt[lane];
#pragma unroll 4
        for (int j2 = 0; j2 < 100; ++j2) {
            float2 pp = *(const float2*)&Ps[wv][2 * j2];
            __hip_bfloat162 vv = *(const __hip_bfloat162*)(vr + 2 * j2);
            od += pp.x * bf2f(vv.x) + pp.y * bf2f(vv.y);
        }
        gacc += od;
    }
    Gp[wv][lane] = gacc;
    __syncthreads();
    if (wv == 0) {
        float s = Gp[0][lane] + Gp[1][lane] + Gp[2][lane] + Gp[3][lane];
        gmean[b * 256 + hd * 64 + lane] = s * (1.0f / 200.0f);
    }
}

// ---------------- heads ----------------
__global__ __launch_bounds__(256) void k_heads(const bf16* __restrict__ lasth,
                                               const float* __restrict__ fcW_pv, const float* __restrict__ fcb_pv,
                                               const float* __restrict__ fcW_s, const float* __restrict__ fcb_s,
                                               float* __restrict__ out) {
    int b = blockIdx.x;
    __shared__ float hl[5][257];
    for (int idx = threadIdx.x; idx < 5 * 256; idx += 256) {
        int k = idx >> 8, h = idx & 255;
        hl[k][h] = bf2f(lasth[((long)k * 256 + b) * 256 + h]);
    }
    __syncthreads();
    int i = threadIdx.x;
    if (i < 210) {
        int k, o, l, c;
        const float* w;
        float bias;
        bool sig = false;
        if (i < 60)       { k = 0; o = i;       w = fcW_pv + o * 256;        bias = fcb_pv[o];       l = o >> 1; c = o & 1; }
        else if (i < 120) { k = 1; o = i - 60;  w = fcW_pv + (60 + o) * 256; bias = fcb_pv[60 + o];  l = o >> 1; c = 2 + (o & 1); }
        else if (i < 150) { k = 2; o = i - 120; w = fcW_s + o * 256;         bias = fcb_s[o];        l = o; c = 4; }
        else if (i < 180) { k = 3; o = i - 150; w = fcW_s + (30 + o) * 256;  bias = fcb_s[30 + o];   l = o; c = 5; sig = true; }
        else              { k = 4; o = i - 180; w = fcW_s + (60 + o) * 256;  bias = fcb_s[60 + o];   l = o; c = 6; sig = true; }
        float acc = bias;
        for (int h = 0; h < 256; ++h) acc += hl[k][h] * w[h];
        if (sig) acc = 1.f / (1.f + expf(-acc));
        out[(long)b * 210 + l * 7 + c] = acc;
    }
}

// ---------------- launch ----------------
extern "C" void kernel_launch(void* const* d_in, const int* in_sizes, int n_in,
                              void* d_out, int out_size, void* d_ws, size_t ws_size,
                              hipStream_t stream) {
    (void)in_sizes; (void)n_in;
    const float* x_feats   = (const float*)d_in[0];
    const float* node_feat = (const float*)d_in[1];
    const int*   edge_idx  = (const int*)d_in[2];
    const float* gcn_W1    = (const float*)d_in[3];
    const float* gcn_b1    = (const float*)d_in[4];
    const float* gcn_W2    = (const float*)d_in[5];
    const float* gcn_b2    = (const float*)d_in[6];
    const float* attn_in_w = (const float*)d_in[7];
    const float* attn_in_b = (const float*)d_in[8];
    const float* attn_out_w= (const float*)d_in[9];
    const float* attn_out_b= (const float*)d_in[10];
    const float* Wih0      = (const float*)d_in[11];
    const float* Wih1      = (const float*)d_in[12];
    const float* Whh       = (const float*)d_in[13];
    const float* bih       = (const float*)d_in[14];
    const float* bhh       = (const float*)d_in[15];
    const float* fcW_pv    = (const float*)d_in[16];
    const float* fcb_pv    = (const float*)d_in[17];
    const float* fcW_s     = (const float*)d_in[18];
    const float* fcb_s     = (const float*)d_in[19];
    float* out = (float*)d_out;

    // ---- workspace (byte offsets); total = 186,966,016 B ----
    const size_t NEEDED = 186966016ULL;
    if (ws_size < NEEDED) {
        k_diag<<<210, 256, 0, stream>>>(out, out_size, (float)(ws_size >> 20));
        return;
    }
    char* base = (char*)d_ws;
    bf16*  Adjb  = (bf16*)(base + 0);            // [256][256][224]   29,360,128
    bf16*  y0    = Adjb;                         // [5][30][256][256] 19,660,800 (after Adjb dead)
    bf16*  m1t   = (bf16*)(base + 29360128);     // [256][256][224]   29,360,128 (later m2t)
    bf16*  m2t   = m1t;
    bf16*  actp  = (bf16*)(base + 58720256);     // [256][256][256]   33,554,432 (h1p -> gp)
    char*  bigb  = base + 92274688;              // 78,643,200: AdjF f32 -> qkv -> zin1
    float* AdjF  = (float*)bigb;                 // [256][200][200] f32
    bf16*  qkv   = (bf16*)bigb;                  // [256][200][768]
    bf16*  zin1  = (bf16*)bigb;                  // [5][30][256][1024]
    bf16*  w2t   = (bf16*)(base + 170917888);    // [256][256]
    bf16*  aiwb  = (bf16*)(base + 171048960);    // [768][256]
    bf16*  wih1b = (bf16*)(base + 171442176);    // [5][1024][256]
    bf16*  whhb  = (bf16*)(base + 174063616);    // [5][2][1024][256]
    bf16*  gpart = (bf16*)(base + 179306496);    // [5][256][1024]
    float* dinv  = (float*)(base + 181927936);   // [256][200]
    int*   degc  = (int*)(base + 182132736);     // [256][200]
    float* gmean = (float*)(base + 182337536);   // [256][256]
    float* gfeat = (float*)(base + 182599680);   // [256][256]
    float* bsum  = (float*)(base + 182861824);   // [5][2][1024]
    bf16*  hz    = (bf16*)(base + 182902784);    // [256][256] zeros
    float* c0    = (float*)(base + 183033856);   // [5][256][256] f32
    float* c1    = (float*)(base + 184344576);   // [5][256][256] f32
    bf16*  h1a   = (bf16*)(base + 185655296);    // [5][256][256]
    bf16*  h1b   = (bf16*)(base + 186310656);    // [5][256][256]

    hipMemsetAsync(AdjF, 0, 40960000, stream);
    hipMemsetAsync(degc, 0, 204800, stream);
    hipMemsetAsync(hz,   0, 131072, stream);
    hipMemsetAsync(c0,   0, 1310720, stream);
    hipMemsetAsync(c1,   0, 1310720, stream);

    // adjacency
    k_deg<<<1600, 256, 0, stream>>>(edge_idx, degc);
    k_dinv<<<200, 256, 0, stream>>>(degc, dinv);
    k_adj<<<1600, 256, 0, stream>>>(edge_idx, dinv, AdjF);
    k_adjself<<<200, 256, 0, stream>>>(dinv, AdjF);
    k_adjconv<<<57344, 256, 0, stream>>>(AdjF, Adjb);
    k_m1t<<<57344, 256, 0, stream>>>(node_feat, gcn_W1, m1t);

    // weight conversions
    k_convT<<<256, 256, 0, stream>>>(gcn_W2, w2t);
    k_conv<<<768, 256, 0, stream>>>(attn_in_w, aiwb, 196608);
    k_conv<<<5120, 256, 0, stream>>>(Wih1, wih1b, 1310720);
    k_conv<<<10240, 256, 0, stream>>>(Whh, whhb, 2621440);
    k_bsum<<<40, 256, 0, stream>>>(bih, bhh, bsum);

    // h1p = relu(Adj @ m1 + b1)          [b: M=256(pad), N=256, K=224]
    mgemm<128, 128, true, false><<<dim3(2, 2, 256), 256, 0, stream>>>(
        Adjb, 57344, 224, m1t, 57344, 224, actp, 65536, 256, gcn_b1, 0, 224, 256);
    // m2t = (h1 @ W2)^T (CT store, pred m<200)
    mgemm<128, 128, false, true><<<dim3(2, 2, 256), 256, 0, stream>>>(
        actp, 65536, 256, w2t, 0, 256, m2t, 57344, 224, nullptr, 0, 256, 200);
    // gp = relu(Adj @ m2 + b2)
    mgemm<128, 128, true, false><<<dim3(2, 2, 256), 256, 0, stream>>>(
        Adjb, 57344, 224, m2t, 57344, 224, actp, 65536, 256, gcn_b2, 0, 224, 256);
    // qkv = g @ attn_in_w^T + b  (compact store, pred m<200)
    mgemm<128, 128, false, false><<<dim3(6, 2, 256), 256, 0, stream>>>(
        actp, 65536, 256, aiwb, 0, 256, qkv, 153600, 768, attn_in_b, 0, 256, 200);

    k_attn<<<1024, 256, 0, stream>>>(qkv, gmean);
    // gfeat = gmean @ attn_out_w^T + attn_out_b
    gemm64<true, float, float, float><<<dim3(4, 4, 1), 256, 0, stream>>>(
        gmean, 0, 256, attn_out_w, 0, 256, gfeat, 0, 256, attn_out_b, 0, 256, 256, 256, 0);
    // gpart[k] = gfeat @ Wih0[k][:,2:]^T + (bih0+bhh0)
    gemm64<true, float, float, bf16><<<dim3(16, 4, 5), 256, 0, stream>>>(
        gfeat, 0, 256, Wih0 + 2, 264192, 258, gpart, 262144, 1024, bsum, 2048, 256, 1024, 256, 0);

    // layer-0 recurrence -> y0 (overwrites dead Adjb)
    for (int t = 0; t < 30; ++t) {
        const bf16* hp = t ? (y0 + (size_t)(t - 1) * 65536) : hz;
        long hpS = t ? 1966080L : 0L;
        k_lstm<0><<<dim3(8, 4, 5), 256, 0, stream>>>(hp, hpS, whhb, gpart, 262144L,
                                                     x_feats, Wih0, c0,
                                                     y0 + (size_t)t * 65536, 1966080L, t);
    }
    // zin1 = y0 @ Wih1^T + (bih1+bhh1)   (overwrites dead qkv)
    mgemm<128, 128, false, false><<<dim3(8, 60, 5), 256, 0, stream>>>(
        y0, 1966080, 256, wih1b, 262144, 256, zin1, 7864320, 1024, bsum + 1024, 2048, 256, 7680);
    // layer-1 recurrence; ping-pong; last hidden in h1b (t=29 odd)
    for (int t = 0; t < 30; ++t) {
        const bf16* hp = (t == 0) ? hz : ((t & 1) ? h1a : h1b);
        long hpS = (t == 0) ? 0L : 65536L;
        bf16* hn = (t & 1) ? h1b : h1a;
        k_lstm<1><<<dim3(8, 4, 5), 256, 0, stream>>>(hp, hpS, whhb, zin1 + (long)t * 262144, 7864320L,
                                                     nullptr, nullptr, c1, hn, 65536L, t);
    }
    k_heads<<<256, 256, 0, stream>>>(h1b, fcW_pv, fcb_pv, fcW_s, fcb_s, out);
}

// Round 4
// 1163.816 us; speedup vs baseline: 3.7096x; 1.4460x over previous
//
#include <hip/hip_runtime.h>
#include <hip/hip_bf16.h>

typedef __hip_bfloat16 bf16;
typedef __bf16 bh8 __attribute__((ext_vector_type(8)));
typedef float f32x4 __attribute__((ext_vector_type(4)));

#define BBATCH 256
#define NN   200
#define EE   1600

#define GLOAD16(gp, lp) __builtin_amdgcn_global_load_lds( \
    (const __attribute__((address_space(1))) void*)(gp),  \
    (__attribute__((address_space(3))) void*)(lp), 16, 0, 0)

__device__ inline float bf2f(bf16 v) { return __bfloat162float(v); }
__device__ inline float ldf(const float* p) { return *p; }
__device__ inline float ldf(const bf16* p) { return __bfloat162float(*p); }
__device__ inline void stf(float* p, float v) { *p = v; }
__device__ inline void stf(bf16* p, float v) { *p = __float2bfloat16(v); }

// ---------------- diagnostic (ws too small) ----------------
__global__ __launch_bounds__(256) void k_diag(float* out, int n, float v) {
    for (int i = blockIdx.x * 256 + threadIdx.x; i < n; i += gridDim.x * 256) out[i] = v;
}

// ---------------- degree / adjacency ----------------
__global__ __launch_bounds__(256) void k_deg(const int* __restrict__ ei, int* __restrict__ cnt) {
    int idx = blockIdx.x * 256 + threadIdx.x;           // B*E
    int b = idx / EE, e = idx % EE;
    int tg = ei[(long)b * 2 * EE + EE + e];
    atomicAdd(&cnt[b * NN + tg], 1);
}

__global__ __launch_bounds__(256) void k_dinv(const int* __restrict__ cnt, float* __restrict__ dinv) {
    int i = blockIdx.x * 256 + threadIdx.x;             // B*N
    dinv[i] = rsqrtf((float)cnt[i] + 1.0f);
}

__global__ __launch_bounds__(256) void k_adj(const int* __restrict__ ei, const float* __restrict__ dinv,
                                             float* __restrict__ AdjF) {
    int idx = blockIdx.x * 256 + threadIdx.x;           // B*E
    int b = idx / EE, e = idx % EE;
    const int* eb = ei + (long)b * 2 * EE;
    int s = eb[e], tg = eb[EE + e];
    // duplicate (s,tg) edges add IDENTICAL values -> order-independent -> deterministic
    atomicAdd(&AdjF[((long)b * NN + tg) * NN + s], dinv[b * NN + tg] * dinv[b * NN + s]);
}

__global__ __launch_bounds__(256) void k_adjself(const float* __restrict__ dinv, float* __restrict__ AdjF) {
    int idx = blockIdx.x * 256 + threadIdx.x;           // B*N
    int b = idx / NN, n = idx % NN;
    float d = dinv[idx];
    atomicAdd(&AdjF[((long)b * NN + n) * NN + n], d * d);
}

// AdjF [b][200][200] f32 -> Adjb [b][256][224] bf16 zero-padded
__global__ __launch_bounds__(256) void k_adjconv(const float* __restrict__ AdjF, bf16* __restrict__ Adjb) {
    long idx = (long)blockIdx.x * 256 + threadIdx.x;    // 256*256*224
    int col = idx % 224;
    int row = (idx / 224) & 255;
    int b = idx / (224 * 256);
    float v = (row < NN && col < NN) ? AdjF[((long)b * NN + row) * NN + col] : 0.f;
    Adjb[idx] = __float2bfloat16(v);
}

// m1t[b][h=256][node k=224] = (node_features @ W1)^T, zero-padded
__global__ __launch_bounds__(256) void k_m1t(const float* __restrict__ nf, const float* __restrict__ W1,
                                             bf16* __restrict__ m1t) {
    long idx = (long)blockIdx.x * 256 + threadIdx.x;    // 256*256*224
    int node = idx % 224;
    int h = (idx / 224) & 255;
    int b = idx / (224 * 256);
    float v = 0.f;
    if (node < NN) {
        const float* x = nf + ((long)b * NN + node) * 4;
        v = x[0] * W1[h] + x[1] * W1[256 + h] + x[2] * W1[512 + h] + x[3] * W1[768 + h];
    }
    m1t[idx] = __float2bfloat16(v);
}

// ---------------- weight conversions ----------------
__global__ __launch_bounds__(256) void k_conv(const float* __restrict__ s, bf16* __restrict__ d, int n) {
    int i = blockIdx.x * 256 + threadIdx.x;
    if (i < n) d[i] = __float2bfloat16(s[i]);
}

__global__ __launch_bounds__(256) void k_convT(const float* __restrict__ W2, bf16* __restrict__ w2t) {
    int i = blockIdx.x * 256 + threadIdx.x;             // 65536: i = n*256+k
    w2t[i] = __float2bfloat16(W2[((i & 255) << 8) + (i >> 8)]);
}

__global__ __launch_bounds__(256) void k_bsum(const float* __restrict__ bih, const float* __restrict__ bhh,
                                              float* __restrict__ bsum) {
    int i = blockIdx.x * 256 + threadIdx.x;             // 10240
    bsum[i] = bih[i] + bhh[i];
}

// ---------------- MFMA GEMM: C = A @ Bt^T (+bias)(+relu), bf16 in/out, f32 accum ----------
template<int BM, int BN, bool RELU, bool CT>
__global__ __launch_bounds__(256)
void mgemm(const bf16* __restrict__ A, long aBatch, int lda,
           const bf16* __restrict__ Bt, long bBatch, int ldb,
           bf16* __restrict__ C, long cBatch, int ldc,
           const float* __restrict__ bias, long biasBatch,
           int K, int Mvalid)
{
    constexpr int ACH = BM / 16, TCH = BM / 16 + BN / 16, PW = TCH / 4;
    constexpr int FM = BM / 32, FN = BN / 32;
    __shared__ bf16 Al[BM][32];
    __shared__ bf16 Bl[BN][32];
    int bz = blockIdx.z;
    const bf16* Ab = A + (long)bz * aBatch + (long)blockIdx.y * BM * lda;
    const bf16* Bb = Bt + (long)bz * bBatch + (long)blockIdx.x * BN * ldb;
    int tid = threadIdx.x, w = tid >> 6, l = tid & 63;
    int wm = w >> 1, wn = w & 1;
    int lrow = l >> 2, lk8 = (l & 3) * 8;
    f32x4 acc[FM][FN] = {};
    for (int k0 = 0; k0 < K; k0 += 32) {
#pragma unroll
        for (int cc = 0; cc < PW; ++cc) {
            int c = w * PW + cc;
            if (c < ACH) GLOAD16(Ab + (long)(c * 16 + lrow) * lda + k0 + lk8, ((char*)&Al[0][0]) + c * 1024);
            else { int bc = c - ACH; GLOAD16(Bb + (long)(bc * 16 + lrow) * ldb + k0 + lk8, ((char*)&Bl[0][0]) + bc * 1024); }
        }
        __syncthreads();
        bh8 af[FM], bfv[FN];
#pragma unroll
        for (int i = 0; i < FM; ++i) af[i] = *(const bh8*)&Al[wm * (BM / 2) + i * 16 + (l & 15)][(l >> 4) * 8];
#pragma unroll
        for (int j = 0; j < FN; ++j) bfv[j] = *(const bh8*)&Bl[wn * (BN / 2) + j * 16 + (l & 15)][(l >> 4) * 8];
#pragma unroll
        for (int i = 0; i < FM; ++i)
#pragma unroll
            for (int j = 0; j < FN; ++j)
                acc[i][j] = __builtin_amdgcn_mfma_f32_16x16x32_bf16(af[i], bfv[j], acc[i][j], 0, 0, 0);
        __syncthreads();
    }
    bf16* Cb = C + (long)bz * cBatch;
    int mq = blockIdx.y * BM + wm * (BM / 2);
    int nq = blockIdx.x * BN + wn * (BN / 2);
#pragma unroll
    for (int i = 0; i < FM; ++i) {
#pragma unroll
        for (int j = 0; j < FN; ++j) {
            int n = nq + j * 16 + (l & 15);
            float bv = bias ? bias[(long)bz * biasBatch + n] : 0.f;
            int m0 = mq + i * 16 + (l >> 4) * 4;
#pragma unroll
            for (int r = 0; r < 4; ++r) {
                int m = m0 + r;
                if (m < Mvalid) {
                    float v = acc[i][j][r] + bv;
                    if (RELU) v = fmaxf(v, 0.f);
                    if (CT) Cb[(long)n * ldc + m] = __float2bfloat16(v);
                    else    Cb[(long)m * ldc + n] = __float2bfloat16(v);
                }
            }
        }
    }
}

// ---------------- MFMA LSTM step ----------
template<int LAYER>
__global__ __launch_bounds__(256)
void k_lstm(const bf16* __restrict__ hprev, long hprevS,
            const bf16* __restrict__ whhb,
            const bf16* __restrict__ zx, long zxS,
            const float* __restrict__ xf,
            const float* __restrict__ Wih0_,
            float* __restrict__ cst,
            bf16* __restrict__ hnext, long hnextS,
            int t)
{
    __shared__ bf16 Al[64][32];
    __shared__ bf16 Bl[128][32];
    __shared__ float Zl[64][132];
    int k5 = blockIdx.z, b0 = blockIdx.y * 64, j0 = blockIdx.x * 32;
    int tid = threadIdx.x, w = tid >> 6, l = tid & 63;
    int wm = w >> 1, wn = w & 1;
    int lrow = l >> 2, lk8 = (l & 3) * 8;
    const bf16* Ab = hprev + (long)k5 * hprevS + (long)b0 * 256;
    const bf16* Bb = whhb + (long)(k5 * 2 + LAYER) * 262144;
    f32x4 acc[2][4] = {};
    for (int k0 = 0; k0 < 256; k0 += 32) {
#pragma unroll
        for (int cc = 0; cc < 3; ++cc) {
            int c = w * 3 + cc;
            if (c < 4) GLOAD16(Ab + (long)(c * 16 + lrow) * 256 + k0 + lk8, ((char*)&Al[0][0]) + c * 1024);
            else {
                int bc = c - 4;
                int gate = bc >> 1;
                int row = gate * 256 + j0 + (bc & 1) * 16 + lrow;
                GLOAD16(Bb + (long)row * 256 + k0 + lk8, ((char*)&Bl[0][0]) + bc * 1024);
            }
        }
        __syncthreads();
        bh8 af[2], bfv[4];
#pragma unroll
        for (int i = 0; i < 2; ++i) af[i] = *(const bh8*)&Al[wm * 32 + i * 16 + (l & 15)][(l >> 4) * 8];
#pragma unroll
        for (int j = 0; j < 4; ++j) bfv[j] = *(const bh8*)&Bl[wn * 64 + j * 16 + (l & 15)][(l >> 4) * 8];
#pragma unroll
        for (int i = 0; i < 2; ++i)
#pragma unroll
            for (int j = 0; j < 4; ++j)
                acc[i][j] = __builtin_amdgcn_mfma_f32_16x16x32_bf16(af[i], bfv[j], acc[i][j], 0, 0, 0);
        __syncthreads();
    }
#pragma unroll
    for (int i = 0; i < 2; ++i)
#pragma unroll
        for (int j = 0; j < 4; ++j)
#pragma unroll
            for (int r = 0; r < 4; ++r)
                Zl[wm * 32 + i * 16 + (l >> 4) * 4 + r][wn * 64 + j * 16 + (l & 15)] = acc[i][j][r];
    __syncthreads();
    int jj = tid & 31, bq = tid >> 5;
    int jg = j0 + jj;
#pragma unroll
    for (int i = 0; i < 8; ++i) {
        int bl = bq + i * 8;
        int bg = b0 + bl;
        const bf16* zp = zx + (long)k5 * zxS + (long)bg * 1024;
        float z[4];
#pragma unroll
        for (int g = 0; g < 4; ++g) z[g] = Zl[bl][g * 32 + jj] + bf2f(zp[g * 256 + jg]);
        if (LAYER == 0) {
            const float* xr = xf + ((long)(k5 * 256 + bg) * 30 + t) * 2;
            float x0 = xr[0], x1 = xr[1];
#pragma unroll
            for (int g = 0; g < 4; ++g) {
                const float* wr = Wih0_ + ((long)k5 * 1024 + g * 256 + jg) * 258;
                z[g] += x0 * wr[0] + x1 * wr[1];
            }
        }
        long ci = ((long)(k5 * 256 + bg)) * 256 + jg;
        float cprev = cst[ci];
        float ig = 1.f / (1.f + expf(-z[0]));
        float fg = 1.f / (1.f + expf(-z[1]));
        float gg = tanhf(z[2]);
        float og = 1.f / (1.f + expf(-z[3]));
        float c = fg * cprev + ig * gg;
        float h = og * tanhf(c);
        cst[ci] = c;
        hnext[(long)k5 * hnextS + (long)bg * 256 + jg] = __float2bfloat16(h);
    }
}

// ---------------- small f32 GEMM (tiny gfeat/gpart) ----------------
template <bool BT, typename TA, typename TB, typename TC>
__global__ __launch_bounds__(256)
void gemm64(const TA* __restrict__ A, long aBatch, int lda,
            const TB* __restrict__ Bm, long bBatch, int ldb,
            TC* __restrict__ C, long cBatch, int ldc,
            const float* __restrict__ bias, long biasBatch,
            int M, int Nn, int K, int flags) {
    __shared__ float As[16][64];
    __shared__ float Bs[16][64];
    int bz = blockIdx.z;
    const TA* Ab = A + (long)bz * aBatch;
    const TB* Bb = Bm + (long)bz * bBatch;
    TC* Cb = C + (long)bz * cBatch;
    int m0 = blockIdx.y * 64, n0 = blockIdx.x * 64;
    int tid = threadIdx.x;
    int tr = tid >> 4, tc = tid & 15;
    float acc[4][4] = {};
    int la_m = tid >> 2;
    int la_k = (tid & 3) * 4;
    for (int k0 = 0; k0 < K; k0 += 16) {
#pragma unroll
        for (int j = 0; j < 4; ++j) {
            int kk = la_k + j;
            float v = 0.f;
            if (m0 + la_m < M && k0 + kk < K) v = ldf(&Ab[(long)(m0 + la_m) * lda + k0 + kk]);
            As[kk][la_m] = v;
        }
        if (!BT) {
            int n = tid & 63, kb = (tid >> 6) * 4;
#pragma unroll
            for (int j = 0; j < 4; ++j) {
                int kk = kb + j;
                float v = 0.f;
                if (k0 + kk < K && n0 + n < Nn) v = ldf(&Bb[(long)(k0 + kk) * ldb + n0 + n]);
                Bs[kk][n] = v;
            }
        } else {
            int n = tid >> 2, kb = (tid & 3) * 4;
#pragma unroll
            for (int j = 0; j < 4; ++j) {
                int kk = kb + j;
                float v = 0.f;
                if (k0 + kk < K && n0 + n < Nn) v = ldf(&Bb[(long)(n0 + n) * ldb + k0 + kk]);
                Bs[kk][n] = v;
            }
        }
        __syncthreads();
#pragma unroll
        for (int kk = 0; kk < 16; ++kk) {
            float4 a4 = *(const float4*)&As[kk][tr * 4];
            float4 b4 = *(const float4*)&Bs[kk][tc * 4];
            float a[4] = {a4.x, a4.y, a4.z, a4.w};
            float bb[4] = {b4.x, b4.y, b4.z, b4.w};
#pragma unroll
            for (int i = 0; i < 4; ++i)
#pragma unroll
                for (int j = 0; j < 4; ++j) acc[i][j] += a[i] * bb[j];
        }
        __syncthreads();
    }
#pragma unroll
    for (int i = 0; i < 4; ++i) {
        int m = m0 + tr * 4 + i;
        if (m >= M) continue;
#pragma unroll
        for (int j = 0; j < 4; ++j) {
            int n = n0 + tc * 4 + j;
            if (n >= Nn) continue;
            float v = acc[i][j];
            if (bias) v += bias[(long)bz * biasBatch + n];
            if (flags & 1) v = fmaxf(v, 0.f);
            stf(&Cb[(long)m * ldc + n], v);
        }
    }
}

// ---------------- MFMA attention, fully reduced to gmean ----------------
// gmean[b][hd*64+d] = (1/200) * sum_q O[q][d] = (1/200) * (colsum_q P) @ V
// One block per (b,hd); 4 waves; QK^T via mfma; softmax in D-frag layout;
// colsum in registers; final colsum@V with coalesced V reads.
__global__ __launch_bounds__(256) void k_attn(const bf16* __restrict__ qkv, float* __restrict__ gmean) {
    int b = blockIdx.x >> 2, hd = blockIdx.x & 3;
    __shared__ bf16 Ks[208][72];       // padded rows; stride 144B spreads bank sets
    __shared__ float CSl[4][208];      // per-wave colsum partials
    __shared__ float Gp[4][64];
    int tid = threadIdx.x, w = tid >> 6, l = tid & 63;
    const bf16* qb = qkv + (long)b * (NN * 768) + hd * 64;
    // stage K (rows >=200 zeroed)
    for (int i = tid; i < 208 * 8; i += 256) {
        int n = i >> 3, g = i & 7;
        uint4 v = make_uint4(0, 0, 0, 0);
        if (n < NN) v = *(const uint4*)(qb + (long)n * 768 + 256 + g * 8);
        *(uint4*)&Ks[n][g * 8] = v;
    }
    __syncthreads();

    float cs[13];
#pragma unroll
    for (int t = 0; t < 13; ++t) cs[t] = 0.f;
    int ln = l & 15, lg = l >> 4;

    for (int qt = w; qt < 13; qt += 4) {           // wave-owned q-tiles
        // A-frags for Q rows qt*16..+15 (clamped), K=64 in two chunks
        int qr = qt * 16 + ln; if (qr > NN - 1) qr = NN - 1;
        bh8 aq0 = *(const bh8*)(qb + (long)qr * 768 + lg * 8);
        bh8 aq1 = *(const bh8*)(qb + (long)qr * 768 + 32 + lg * 8);
        f32x4 s[13];
#pragma unroll
        for (int t = 0; t < 13; ++t) s[t] = f32x4{0.f, 0.f, 0.f, 0.f};
#pragma unroll
        for (int t = 0; t < 13; ++t) {
            bh8 b0 = *(const bh8*)&Ks[t * 16 + ln][lg * 8];
            bh8 b1 = *(const bh8*)&Ks[t * 16 + ln][32 + lg * 8];
            s[t] = __builtin_amdgcn_mfma_f32_16x16x32_bf16(aq0, b0, s[t], 0, 0, 0);
            s[t] = __builtin_amdgcn_mfma_f32_16x16x32_bf16(aq1, b1, s[t], 0, 0, 0);
        }
        // softmax over n (cols): lane holds col n = t*16+ln, rows q = qt*16+lg*4+r
        float mx[4] = {-1e30f, -1e30f, -1e30f, -1e30f};
#pragma unroll
        for (int t = 0; t < 13; ++t) {
            bool vn = (t < 12) | (ln < 8);         // n < 200
#pragma unroll
            for (int r = 0; r < 4; ++r) {
                float v = s[t][r] * 0.125f;
                s[t][r] = v;
                if (vn) mx[r] = fmaxf(mx[r], v);
            }
        }
#pragma unroll
        for (int off = 1; off < 16; off <<= 1)
#pragma unroll
            for (int r = 0; r < 4; ++r) mx[r] = fmaxf(mx[r], __shfl_xor(mx[r], off));
        float sum[4] = {0.f, 0.f, 0.f, 0.f};
#pragma unroll
        for (int t = 0; t < 13; ++t) {
            bool vn = (t < 12) | (ln < 8);
#pragma unroll
            for (int r = 0; r < 4; ++r) {
                float e = vn ? expf(s[t][r] - mx[r]) : 0.f;
                s[t][r] = e;
                sum[r] += e;
            }
        }
#pragma unroll
        for (int off = 1; off < 16; off <<= 1)
#pragma unroll
            for (int r = 0; r < 4; ++r) sum[r] += __shfl_xor(sum[r], off);
        float inv[4];
#pragma unroll
        for (int r = 0; r < 4; ++r) inv[r] = 1.f / sum[r];
        // colsum accumulate (exclude padded q rows)
#pragma unroll
        for (int r = 0; r < 4; ++r) {
            int q = qt * 16 + lg * 4 + r;
            if (q < NN) {
#pragma unroll
                for (int t = 0; t < 13; ++t) cs[t] += s[t][r] * inv[r];
            }
        }
    }
    // reduce colsum across the 4 row-groups (lanes ^16, ^32)
#pragma unroll
    for (int t = 0; t < 13; ++t) {
        cs[t] += __shfl_xor(cs[t], 16);
        cs[t] += __shfl_xor(cs[t], 32);
    }
    if (l < 16) {
#pragma unroll
        for (int t = 0; t < 13; ++t) CSl[w][t * 16 + l] = cs[t];
    }
    __syncthreads();
    // gmean[d] = (1/200) * sum_n CS[n] * V[n][d]; wave w covers n in [w*50, w*50+50)
    float part = 0.f;
    for (int n = w * 50; n < w * 50 + 50; ++n) {
        float csn = CSl[0][n] + CSl[1][n] + CSl[2][n] + CSl[3][n];
        part += csn * bf2f(qb[(long)n * 768 + 512 + l]);
    }
    Gp[w][l] = part;
    __syncthreads();
    if (w == 0) {
        float tot = Gp[0][l] + Gp[1][l] + Gp[2][l] + Gp[3][l];
        gmean[b * 256 + hd * 64 + l] = tot * (1.0f / 200.0f);
    }
}

// ---------------- heads ----------------
__global__ __launch_bounds__(256) void k_heads(const bf16* __restrict__ lasth,
                                               const float* __restrict__ fcW_pv, const float* __restrict__ fcb_pv,
                                               const float* __restrict__ fcW_s, const float* __restrict__ fcb_s,
                                               float* __restrict__ out) {
    int b = blockIdx.x;
    __shared__ float hl[5][257];
    for (int idx = threadIdx.x; idx < 5 * 256; idx += 256) {
        int k = idx >> 8, h = idx & 255;
        hl[k][h] = bf2f(lasth[((long)k * 256 + b) * 256 + h]);
    }
    __syncthreads();
    int i = threadIdx.x;
    if (i < 210) {
        int k, o, l, c;
        const float* w;
        float bias;
        bool sig = false;
        if (i < 60)       { k = 0; o = i;       w = fcW_pv + o * 256;        bias = fcb_pv[o];       l = o >> 1; c = o & 1; }
        else if (i < 120) { k = 1; o = i - 60;  w = fcW_pv + (60 + o) * 256; bias = fcb_pv[60 + o];  l = o >> 1; c = 2 + (o & 1); }
        else if (i < 150) { k = 2; o = i - 120; w = fcW_s + o * 256;         bias = fcb_s[o];        l = o; c = 4; }
        else if (i < 180) { k = 3; o = i - 150; w = fcW_s + (30 + o) * 256;  bias = fcb_s[30 + o];   l = o; c = 5; sig = true; }
        else              { k = 4; o = i - 180; w = fcW_s + (60 + o) * 256;  bias = fcb_s[60 + o];   l = o; c = 6; sig = true; }
        float acc = bias;
        for (int h = 0; h < 256; ++h) acc += hl[k][h] * w[h];
        if (sig) acc = 1.f / (1.f + expf(-acc));
        out[(long)b * 210 + l * 7 + c] = acc;
    }
}

// ---------------- launch ----------------
extern "C" void kernel_launch(void* const* d_in, const int* in_sizes, int n_in,
                              void* d_out, int out_size, void* d_ws, size_t ws_size,
                              hipStream_t stream) {
    (void)in_sizes; (void)n_in;
    const float* x_feats   = (const float*)d_in[0];
    const float* node_feat = (const float*)d_in[1];
    const int*   edge_idx  = (const int*)d_in[2];
    const float* gcn_W1    = (const float*)d_in[3];
    const float* gcn_b1    = (const float*)d_in[4];
    const float* gcn_W2    = (const float*)d_in[5];
    const float* gcn_b2    = (const float*)d_in[6];
    const float* attn_in_w = (const float*)d_in[7];
    const float* attn_in_b = (const float*)d_in[8];
    const float* attn_out_w= (const float*)d_in[9];
    const float* attn_out_b= (const float*)d_in[10];
    const float* Wih0      = (const float*)d_in[11];
    const float* Wih1      = (const float*)d_in[12];
    const float* Whh       = (const float*)d_in[13];
    const float* bih       = (const float*)d_in[14];
    const float* bhh       = (const float*)d_in[15];
    const float* fcW_pv    = (const float*)d_in[16];
    const float* fcb_pv    = (const float*)d_in[17];
    const float* fcW_s     = (const float*)d_in[18];
    const float* fcb_s     = (const float*)d_in[19];
    float* out = (float*)d_out;

    // ---- workspace (byte offsets); total = 186,966,016 B ----
    const size_t NEEDED = 186966016ULL;
    if (ws_size < NEEDED) {
        k_diag<<<210, 256, 0, stream>>>(out, out_size, (float)(ws_size >> 20));
        return;
    }
    char* base = (char*)d_ws;
    bf16*  Adjb  = (bf16*)(base + 0);            // [256][256][224]
    bf16*  y0    = Adjb;                         // [5][30][256][256] (after Adjb dead)
    bf16*  m1t   = (bf16*)(base + 29360128);     // [256][256][224] (later m2t)
    bf16*  m2t   = m1t;
    bf16*  actp  = (bf16*)(base + 58720256);     // [256][256][256] (h1p -> gp)
    char*  bigb  = base + 92274688;              // AdjF f32 -> qkv -> zin1
    float* AdjF  = (float*)bigb;
    bf16*  qkv   = (bf16*)bigb;
    bf16*  zin1  = (bf16*)bigb;
    bf16*  w2t   = (bf16*)(base + 170917888);
    bf16*  aiwb  = (bf16*)(base + 171048960);
    bf16*  wih1b = (bf16*)(base + 171442176);
    bf16*  whhb  = (bf16*)(base + 174063616);
    bf16*  gpart = (bf16*)(base + 179306496);
    float* dinv  = (float*)(base + 181927936);
    int*   degc  = (int*)(base + 182132736);
    float* gmean = (float*)(base + 182337536);
    float* gfeat = (float*)(base + 182599680);
    float* bsum  = (float*)(base + 182861824);
    bf16*  hz    = (bf16*)(base + 182902784);
    float* c0    = (float*)(base + 183033856);
    float* c1    = (float*)(base + 184344576);
    bf16*  h1a   = (bf16*)(base + 185655296);
    bf16*  h1b   = (bf16*)(base + 186310656);

    hipMemsetAsync(AdjF, 0, 40960000, stream);
    hipMemsetAsync(degc, 0, 204800, stream);
    hipMemsetAsync(hz,   0, 131072, stream);
    hipMemsetAsync(c0,   0, 1310720, stream);
    hipMemsetAsync(c1,   0, 1310720, stream);

    k_deg<<<1600, 256, 0, stream>>>(edge_idx, degc);
    k_dinv<<<200, 256, 0, stream>>>(degc, dinv);
    k_adj<<<1600, 256, 0, stream>>>(edge_idx, dinv, AdjF);
    k_adjself<<<200, 256, 0, stream>>>(dinv, AdjF);
    k_adjconv<<<57344, 256, 0, stream>>>(AdjF, Adjb);
    k_m1t<<<57344, 256, 0, stream>>>(node_feat, gcn_W1, m1t);

    k_convT<<<256, 256, 0, stream>>>(gcn_W2, w2t);
    k_conv<<<768, 256, 0, stream>>>(attn_in_w, aiwb, 196608);
    k_conv<<<5120, 256, 0, stream>>>(Wih1, wih1b, 1310720);
    k_conv<<<10240, 256, 0, stream>>>(Whh, whhb, 2621440);
    k_bsum<<<40, 256, 0, stream>>>(bih, bhh, bsum);

    mgemm<128, 128, true, false><<<dim3(2, 2, 256), 256, 0, stream>>>(
        Adjb, 57344, 224, m1t, 57344, 224, actp, 65536, 256, gcn_b1, 0, 224, 256);
    mgemm<128, 128, false, true><<<dim3(2, 2, 256), 256, 0, stream>>>(
        actp, 65536, 256, w2t, 0, 256, m2t, 57344, 224, nullptr, 0, 256, 200);
    mgemm<128, 128, true, false><<<dim3(2, 2, 256), 256, 0, stream>>>(
        Adjb, 57344, 224, m2t, 57344, 224, actp, 65536, 256, gcn_b2, 0, 224, 256);
    mgemm<128, 128, false, false><<<dim3(6, 2, 256), 256, 0, stream>>>(
        actp, 65536, 256, aiwb, 0, 256, qkv, 153600, 768, attn_in_b, 0, 256, 200);

    k_attn<<<1024, 256, 0, stream>>>(qkv, gmean);
    gemm64<true, float, float, float><<<dim3(4, 4, 1), 256, 0, stream>>>(
        gmean, 0, 256, attn_out_w, 0, 256, gfeat, 0, 256, attn_out_b, 0, 256, 256, 256, 0);
    gemm64<true, float, float, bf16><<<dim3(16, 4, 5), 256, 0, stream>>>(
        gfeat, 0, 256, Wih0 + 2, 264192, 258, gpart, 262144, 1024, bsum, 2048, 256, 1024, 256, 0);

    for (int t = 0; t < 30; ++t) {
        const bf16* hp = t ? (y0 + (size_t)(t - 1) * 65536) : hz;
        long hpS = t ? 1966080L : 0L;
        k_lstm<0><<<dim3(8, 4, 5), 256, 0, stream>>>(hp, hpS, whhb, gpart, 262144L,
                                                     x_feats, Wih0, c0,
                                                     y0 + (size_t)t * 65536, 1966080L, t);
    }
    mgemm<128, 128, false, false><<<dim3(8, 60, 5), 256, 0, stream>>>(
        y0, 1966080, 256, wih1b, 262144, 256, zin1, 7864320, 1024, bsum + 1024, 2048, 256, 7680);
    for (int t = 0; t < 30; ++t) {
        const bf16* hp = (t == 0) ? hz : ((t & 1) ? h1a : h1b);
        long hpS = (t == 0) ? 0L : 65536L;
        bf16* hn = (t & 1) ? h1b : h1a;
        k_lstm<1><<<dim3(8, 4, 5), 256, 0, stream>>>(hp, hpS, whhb, zin1 + (long)t * 262144, 7864320L,
                                                     nullptr, nullptr, c1, hn, 65536L, t);
    }
    k_heads<<<256, 256, 0, stream>>>(h1b, fcW_pv, fcb_pv, fcW_s, fcb_s, out);
}